// Round 2
// baseline (1451.993 us; speedup 1.0000x reference)
//
#include <hip/hip_runtime.h>
#include <math.h>

constexpr int Hc = 80, Wc = 80, Bn = 4, C1 = 256, C2 = 256;
constexpr int HWn = Hc * Wc;          // 6400
constexpr int NPIX = Bn * HWn;        // 25600
constexpr int OFFC = 27;

// ---------------- kernel 0: weight transpose -> wT[p][c][o] ----------------
__global__ __launch_bounds__(256) void k_wtrans(const float* __restrict__ weight,
                                                float* __restrict__ wT)
{
    int e = blockIdx.x * 256 + threadIdx.x;   // 0 .. 589823
    int o = e & 255;
    int c = (e >> 8) & 255;
    int p = e >> 16;
    wT[e] = weight[(o * C1 + c) * 9 + p];
}

// ---------------- kernel 1: offset conv (3x3, C1->27, SAME) ----------------
__global__ __launch_bounds__(256) void k_offconv(const float* __restrict__ x,
                                                 const float* __restrict__ w_off,
                                                 const float* __restrict__ b_off,
                                                 float* __restrict__ off)
{
    int t = blockIdx.x * 256 + threadIdx.x;   // 0 .. 691199
    int w  = t % Wc;
    int h  = (t / Wc) % Hc;
    int ch = (t / HWn) % OFFC;
    int b  = t / (HWn * OFFC);
    float acc = b_off[ch];
    const float* xb = x + (size_t)b * C1 * HWn;
    const float* wp = w_off + (size_t)ch * C1 * 9;
    for (int c = 0; c < C1; ++c) {
        const float* xp = xb + c * HWn;
        const float* wc = wp + c * 9;
        #pragma unroll
        for (int kh = 0; kh < 3; ++kh) {
            int r = h - 1 + kh;
            if (r < 0 || r >= Hc) continue;
            #pragma unroll
            for (int kw = 0; kw < 3; ++kw) {
                int cl = w - 1 + kw;
                if (cl < 0 || cl >= Wc) continue;
                acc = fmaf(xp[r * Wc + cl], wc[kh * 3 + kw], acc);
            }
        }
    }
    off[t] = acc;
}

// ------------- kernel 2: deformable gather + implicit GEMM -------------
// M=25600 pixels, N=256 oc, K=2304 (p-major: k = p*256 + c)
// block: 32 pixels x 256 oc, BK=32, 256 threads, 4x8 microtile
__global__ __launch_bounds__(256) void k_dconv(const float* __restrict__ x,
                                               const float* __restrict__ off,
                                               const float* __restrict__ wT,
                                               const float* __restrict__ bias,
                                               float* __restrict__ out)
{
    __shared__ __align__(16) float wS[32 * 256];  // [k][o]
    __shared__ __align__(16) float pS[32 * 32];   // [k][pix]
    __shared__ int    sCrd[32 * 9];
    __shared__ float4 sW4[32 * 9];

    int tid = threadIdx.x;
    int m0  = blockIdx.x * 32;
    int b   = m0 / HWn;           // uniform per block (6400 % 32 == 0)
    int hw0 = m0 - b * HWn;

    // ---- per-(pixel, p) bilinear metadata ----
    for (int idx = tid; idx < 32 * 9; idx += 256) {
        int pix = idx / 9;
        int p   = idx - pix * 9;
        int hw  = hw0 + pix;
        int h = hw / Wc, w = hw - h * Wc;
        int ii = p / 3, jj = p - ii * 3;
        const float* ob = off + (size_t)b * OFFC * HWn + hw;
        float dy = ob[(2 * p) * HWn];
        float dx = ob[(2 * p + 1) * HWn];
        float mv = ob[(18 + p) * HWn];
        float mask = 1.0f / (1.0f + expf(-mv));
        float ys = dy + (float)(h - 1 + ii);
        float xs = dx + (float)(w - 1 + jj);
        float y0f = floorf(ys), x0f = floorf(xs);
        float wy = ys - y0f, wx = xs - x0f;
        int y0 = (int)y0f, x0 = (int)x0f;
        int y1 = y0 + 1, x1 = x0 + 1;
        float vy0 = (y0 >= 0 && y0 < Hc) ? 1.f : 0.f;
        float vy1 = (y1 >= 0 && y1 < Hc) ? 1.f : 0.f;
        float vx0 = (x0 >= 0 && x0 < Wc) ? 1.f : 0.f;
        float vx1 = (x1 >= 0 && x1 < Wc) ? 1.f : 0.f;
        float4 wv;
        wv.x = mask * (1.f - wy) * (1.f - wx) * vy0 * vx0;
        wv.y = mask * (1.f - wy) * wx         * vy0 * vx1;
        wv.z = mask * wy         * (1.f - wx) * vy1 * vx0;
        wv.w = mask * wy         * wx         * vy1 * vx1;
        int cy0 = min(max(y0, 0), Hc - 1), cy1 = min(max(y1, 0), Hc - 1);
        int cx0 = min(max(x0, 0), Wc - 1), cx1 = min(max(x1, 0), Wc - 1);
        sCrd[idx] = cy0 | (cy1 << 8) | (cx0 << 16) | (cx1 << 24);
        sW4[idx]  = wv;
    }
    __syncthreads();

    float acc[4][8];
    #pragma unroll
    for (int i = 0; i < 4; ++i)
        #pragma unroll
        for (int j = 0; j < 8; ++j) acc[i][j] = 0.f;

    int pixg  = tid >> 5;   // GEMM: 4-pixel group
    int ocg   = tid & 31;   // GEMM: 8-oc group
    int pix_s = tid & 31;   // staging: pixel (lane dim -> near-coalesced gather)
    int g     = tid >> 5;   // staging: c-group (4 c each)

    const float* xb = x + (size_t)b * C1 * HWn;

    for (int p = 0; p < 9; ++p) {
        int crd   = sCrd[pix_s * 9 + p];
        float4 wv = sW4[pix_s * 9 + p];
        int cy0 = crd & 255, cy1 = (crd >> 8) & 255;
        int cx0 = (crd >> 16) & 255, cx1 = (crd >> 24) & 255;
        int o00 = cy0 * Wc + cx0, o01 = cy0 * Wc + cx1;
        int o10 = cy1 * Wc + cx0, o11 = cy1 * Wc + cx1;
        for (int cc = 0; cc < 8; ++cc) {
            int c0 = cc * 32;
            __syncthreads();   // previous GEMM done before overwrite
            // stage weight tile wT[p][c0:c0+32][0:256] -> wS (coalesced)
            const float4* wsrc = (const float4*)(wT + ((size_t)p * C1 + c0) * C2);
            float4* wdst = (float4*)wS;
            #pragma unroll
            for (int j = 0; j < 8; ++j)
                wdst[tid + 256 * j] = wsrc[tid + 256 * j];
            // stage patch tile: bilinear gather, lanes along pixels
            #pragma unroll
            for (int q = 0; q < 4; ++q) {
                int cl = g * 4 + q;
                const float* xp = xb + (size_t)(c0 + cl) * HWn;
                float v = wv.x * xp[o00] + wv.y * xp[o01]
                        + wv.z * xp[o10] + wv.w * xp[o11];
                pS[cl * 32 + pix_s] = v;
            }
            __syncthreads();
            // GEMM: 32 k-steps
            #pragma unroll
            for (int k = 0; k < 32; ++k) {
                float4 av = *(const float4*)&pS[k * 32 + pixg * 4];
                float4 b0 = *(const float4*)&wS[k * 256 + ocg * 8];
                float4 b1 = *(const float4*)&wS[k * 256 + ocg * 8 + 4];
                float bb[8] = {b0.x, b0.y, b0.z, b0.w, b1.x, b1.y, b1.z, b1.w};
                #pragma unroll
                for (int j = 0; j < 8; ++j) {
                    acc[0][j] = fmaf(av.x, bb[j], acc[0][j]);
                    acc[1][j] = fmaf(av.y, bb[j], acc[1][j]);
                    acc[2][j] = fmaf(av.z, bb[j], acc[2][j]);
                    acc[3][j] = fmaf(av.w, bb[j], acc[3][j]);
                }
            }
        }
    }
    // epilogue: +bias, store float4 along w
    #pragma unroll
    for (int j = 0; j < 8; ++j) {
        int oc = ocg * 8 + j;
        float bs = bias[oc];
        float4 v;
        v.x = acc[0][j] + bs;
        v.y = acc[1][j] + bs;
        v.z = acc[2][j] + bs;
        v.w = acc[3][j] + bs;
        *(float4*)&out[(size_t)(b * C2 + oc) * HWn + hw0 + pixg * 4] = v;
    }
}

// ---------------- kernel 3: BN stats (per-channel mean, invstd) ----------------
__global__ __launch_bounds__(256) void k_bnstats(const float* __restrict__ out,
                                                 float* __restrict__ stats)
{
    int oc = blockIdx.x;
    double s = 0.0, ss = 0.0;
    for (int i = threadIdx.x; i < NPIX; i += 256) {
        int bb = i / HWn;
        int hw = i - bb * HWn;
        float v = out[(size_t)(bb * C2 + oc) * HWn + hw];
        s  += (double)v;
        ss += (double)v * (double)v;
    }
    __shared__ double ls[256], lss[256];
    ls[threadIdx.x] = s; lss[threadIdx.x] = ss;
    __syncthreads();
    for (int st = 128; st > 0; st >>= 1) {
        if (threadIdx.x < st) {
            ls[threadIdx.x]  += ls[threadIdx.x + st];
            lss[threadIdx.x] += lss[threadIdx.x + st];
        }
        __syncthreads();
    }
    if (threadIdx.x == 0) {
        double mean = ls[0] / (double)NPIX;
        double var  = lss[0] / (double)NPIX - mean * mean;
        stats[oc]       = (float)mean;
        stats[256 + oc] = (float)(1.0 / sqrt(var + 1e-5));
    }
}

// ---------------- kernel 4: BN normalize + affine + SiLU (in-place) ----------------
__global__ __launch_bounds__(256) void k_bnsilu(float* __restrict__ out,
                                                const float* __restrict__ stats,
                                                const float* __restrict__ gamma,
                                                const float* __restrict__ beta)
{
    int n4 = (Bn * C2 * HWn) / 4;
    for (int i = blockIdx.x * blockDim.x + threadIdx.x; i < n4;
         i += gridDim.x * blockDim.x) {
        float4 v = ((float4*)out)[i];
        int e  = i * 4;
        int oc = (e / HWn) & 255;
        float mean = stats[oc];
        float gs   = gamma[oc] * stats[256 + oc];
        float bt   = beta[oc];
        float y;
        y = (v.x - mean) * gs + bt; v.x = y / (1.f + expf(-y));
        y = (v.y - mean) * gs + bt; v.y = y / (1.f + expf(-y));
        y = (v.z - mean) * gs + bt; v.z = y / (1.f + expf(-y));
        y = (v.w - mean) * gs + bt; v.w = y / (1.f + expf(-y));
        ((float4*)out)[i] = v;
    }
}

extern "C" void kernel_launch(void* const* d_in, const int* in_sizes, int n_in,
                              void* d_out, int out_size, void* d_ws, size_t ws_size,
                              hipStream_t stream)
{
    const float* x      = (const float*)d_in[0];
    const float* w_off  = (const float*)d_in[1];
    const float* b_off  = (const float*)d_in[2];
    const float* weight = (const float*)d_in[3];
    const float* bias   = (const float*)d_in[4];
    const float* gamma  = (const float*)d_in[5];
    const float* beta   = (const float*)d_in[6];
    float* out = (float*)d_out;

    float* ws    = (float*)d_ws;
    float* off   = ws;                       // 691200 floats
    float* wT    = ws + 691200;              // 589824 floats
    float* stats = ws + 691200 + 589824;     // 512 floats
    // total ws usage: ~5.13 MB

    k_wtrans  <<<2304, 256, 0, stream>>>(weight, wT);
    k_offconv <<<2700, 256, 0, stream>>>(x, w_off, b_off, off);
    k_dconv   <<<NPIX / 32, 256, 0, stream>>>(x, off, wT, bias, out);
    k_bnstats <<<256, 256, 0, stream>>>(out, stats);
    k_bnsilu  <<<2048, 256, 0, stream>>>(out, stats, gamma, beta);
}

// Round 3
// 1077.205 us; speedup vs baseline: 1.3479x; 1.3479x over previous
//
#include <hip/hip_runtime.h>
#include <math.h>

constexpr int Hc = 80, Wc = 80, Bn = 4, C1 = 256, C2 = 256;
constexpr int HWn = Hc * Wc;          // 6400
constexpr int NPIX = Bn * HWn;        // 25600
constexpr int OFFC = 27;

// ---------------- kernel 0: weight transpose -> wT[p][c][o] ----------------
__global__ __launch_bounds__(256) void k_wtrans(const float* __restrict__ weight,
                                                float* __restrict__ wT)
{
    int e = blockIdx.x * 256 + threadIdx.x;   // 0 .. 589823
    int o = e & 255;
    int c = (e >> 8) & 255;
    int p = e >> 16;
    wT[e] = weight[(o * C1 + c) * 9 + p];
}

// ---------------- kernel 1a: init off buffer with b_off ----------------
__global__ __launch_bounds__(256) void k_offinit(const float* __restrict__ b_off,
                                                 float* __restrict__ off)
{
    int t = blockIdx.x * 256 + threadIdx.x;   // 0 .. 691199
    int ch = (t / HWn) % OFFC;
    off[t] = b_off[ch];
}

// ---------------- kernel 1b: offset conv v2 (LDS-tiled, c-split 4) ----------------
// grid 400: (5 wtiles x 5 htiles x 4 b x 4 cgroups); 16x16 pixels/block;
// 27 fp32 accumulators/thread; weights are thread-uniform -> scalar loads;
// partials atomicAdd'ed into bias-pre-initialized off.
__global__ __launch_bounds__(256) void k_offconv2(const float* __restrict__ x,
                                                  const float* __restrict__ w_off,
                                                  float* __restrict__ off)
{
    __shared__ float xs[8][18][18];   // 10368 B

    int tid  = threadIdx.x;
    int bidx = blockIdx.x;                 // 0..399
    int wt = bidx % 5;
    int ht = (bidx / 5) % 5;
    int b  = (bidx / 25) % 4;
    int cg = bidx / 100;                   // 0..3
    int h0 = ht * 16, w0 = wt * 16;
    int c0 = cg * 64;
    int ph = tid >> 4, pw = tid & 15;

    float acc[27];
    #pragma unroll
    for (int ch = 0; ch < 27; ++ch) acc[ch] = 0.f;

    const float* xb = x + (size_t)b * C1 * HWn;

    for (int cc = 0; cc < 8; ++cc) {       // 8 chunks of 8 channels
        __syncthreads();
        // stage x[c0+cc*8 .. +8][h0-1..h0+16][w0-1..w0+16] with zero halo
        for (int idx = tid; idx < 8 * 324; idx += 256) {
            int cl  = idx / 324;
            int rem = idx - cl * 324;
            int r   = rem / 18;
            int col = rem - r * 18;
            int gh = h0 - 1 + r, gw = w0 - 1 + col;
            float v = 0.f;
            if (gh >= 0 && gh < Hc && gw >= 0 && gw < Wc)
                v = xb[(size_t)(c0 + cc * 8 + cl) * HWn + gh * Wc + gw];
            xs[cl][r][col] = v;
        }
        __syncthreads();
        #pragma unroll
        for (int cl = 0; cl < 8; ++cl) {
            float xr[9];
            #pragma unroll
            for (int kh = 0; kh < 3; ++kh)
                #pragma unroll
                for (int kw = 0; kw < 3; ++kw)
                    xr[kh * 3 + kw] = xs[cl][ph + kh][pw + kw];
            int c = c0 + cc * 8 + cl;
            const float* wp = w_off + (size_t)c * 9;   // + ch*C1*9
            #pragma unroll
            for (int ch = 0; ch < 27; ++ch) {
                const float* wc = wp + (size_t)ch * C1 * 9;  // uniform -> s_load
                #pragma unroll
                for (int p = 0; p < 9; ++p)
                    acc[ch] = fmaf(xr[p], wc[p], acc[ch]);
            }
        }
    }

    int hw = (h0 + ph) * Wc + (w0 + pw);
    float* ob = off + (size_t)b * OFFC * HWn + hw;
    #pragma unroll
    for (int ch = 0; ch < 27; ++ch)
        atomicAdd(ob + (size_t)ch * HWn, acc[ch]);
}

// ------------- kernel 2: deformable gather + implicit GEMM -------------
// M=25600 pixels, N=256 oc, K=2304 (p-major: k = p*256 + c)
// block: 32 pixels x 256 oc, BK=32, 256 threads, 4x8 microtile
__global__ __launch_bounds__(256) void k_dconv(const float* __restrict__ x,
                                               const float* __restrict__ off,
                                               const float* __restrict__ wT,
                                               const float* __restrict__ bias,
                                               float* __restrict__ out)
{
    __shared__ __align__(16) float wS[32 * 256];  // [k][o]
    __shared__ __align__(16) float pS[32 * 32];   // [k][pix]
    __shared__ int    sCrd[32 * 9];
    __shared__ float4 sW4[32 * 9];

    int tid = threadIdx.x;
    int m0  = blockIdx.x * 32;
    int b   = m0 / HWn;           // uniform per block (6400 % 32 == 0)
    int hw0 = m0 - b * HWn;

    // ---- per-(pixel, p) bilinear metadata ----
    for (int idx = tid; idx < 32 * 9; idx += 256) {
        int pix = idx / 9;
        int p   = idx - pix * 9;
        int hw  = hw0 + pix;
        int h = hw / Wc, w = hw - h * Wc;
        int ii = p / 3, jj = p - ii * 3;
        const float* ob = off + (size_t)b * OFFC * HWn + hw;
        float dy = ob[(2 * p) * HWn];
        float dx = ob[(2 * p + 1) * HWn];
        float mv = ob[(18 + p) * HWn];
        float mask = 1.0f / (1.0f + expf(-mv));
        float ys = dy + (float)(h - 1 + ii);
        float xs = dx + (float)(w - 1 + jj);
        float y0f = floorf(ys), x0f = floorf(xs);
        float wy = ys - y0f, wx = xs - x0f;
        int y0 = (int)y0f, x0 = (int)x0f;
        int y1 = y0 + 1, x1 = x0 + 1;
        float vy0 = (y0 >= 0 && y0 < Hc) ? 1.f : 0.f;
        float vy1 = (y1 >= 0 && y1 < Hc) ? 1.f : 0.f;
        float vx0 = (x0 >= 0 && x0 < Wc) ? 1.f : 0.f;
        float vx1 = (x1 >= 0 && x1 < Wc) ? 1.f : 0.f;
        float4 wv;
        wv.x = mask * (1.f - wy) * (1.f - wx) * vy0 * vx0;
        wv.y = mask * (1.f - wy) * wx         * vy0 * vx1;
        wv.z = mask * wy         * (1.f - wx) * vy1 * vx0;
        wv.w = mask * wy         * wx         * vy1 * vx1;
        int cy0 = min(max(y0, 0), Hc - 1), cy1 = min(max(y1, 0), Hc - 1);
        int cx0 = min(max(x0, 0), Wc - 1), cx1 = min(max(x1, 0), Wc - 1);
        sCrd[idx] = cy0 | (cy1 << 8) | (cx0 << 16) | (cx1 << 24);
        sW4[idx]  = wv;
    }
    __syncthreads();

    float acc[4][8];
    #pragma unroll
    for (int i = 0; i < 4; ++i)
        #pragma unroll
        for (int j = 0; j < 8; ++j) acc[i][j] = 0.f;

    int pixg  = tid >> 5;   // GEMM: 4-pixel group
    int ocg   = tid & 31;   // GEMM: 8-oc group
    int pix_s = tid & 31;   // staging: pixel (lane dim -> near-coalesced gather)
    int g     = tid >> 5;   // staging: c-group (4 c each)

    const float* xb = x + (size_t)b * C1 * HWn;

    for (int p = 0; p < 9; ++p) {
        int crd   = sCrd[pix_s * 9 + p];
        float4 wv = sW4[pix_s * 9 + p];
        int cy0 = crd & 255, cy1 = (crd >> 8) & 255;
        int cx0 = (crd >> 16) & 255, cx1 = (crd >> 24) & 255;
        int o00 = cy0 * Wc + cx0, o01 = cy0 * Wc + cx1;
        int o10 = cy1 * Wc + cx0, o11 = cy1 * Wc + cx1;
        for (int cc = 0; cc < 8; ++cc) {
            int c0 = cc * 32;
            __syncthreads();   // previous GEMM done before overwrite
            // stage weight tile wT[p][c0:c0+32][0:256] -> wS (coalesced)
            const float4* wsrc = (const float4*)(wT + ((size_t)p * C1 + c0) * C2);
            float4* wdst = (float4*)wS;
            #pragma unroll
            for (int j = 0; j < 8; ++j)
                wdst[tid + 256 * j] = wsrc[tid + 256 * j];
            // stage patch tile: bilinear gather, lanes along pixels
            #pragma unroll
            for (int q = 0; q < 4; ++q) {
                int cl = g * 4 + q;
                const float* xp = xb + (size_t)(c0 + cl) * HWn;
                float v = wv.x * xp[o00] + wv.y * xp[o01]
                        + wv.z * xp[o10] + wv.w * xp[o11];
                pS[cl * 32 + pix_s] = v;
            }
            __syncthreads();
            // GEMM: 32 k-steps
            #pragma unroll
            for (int k = 0; k < 32; ++k) {
                float4 av = *(const float4*)&pS[k * 32 + pixg * 4];
                float4 b0 = *(const float4*)&wS[k * 256 + ocg * 8];
                float4 b1 = *(const float4*)&wS[k * 256 + ocg * 8 + 4];
                float bb[8] = {b0.x, b0.y, b0.z, b0.w, b1.x, b1.y, b1.z, b1.w};
                #pragma unroll
                for (int j = 0; j < 8; ++j) {
                    acc[0][j] = fmaf(av.x, bb[j], acc[0][j]);
                    acc[1][j] = fmaf(av.y, bb[j], acc[1][j]);
                    acc[2][j] = fmaf(av.z, bb[j], acc[2][j]);
                    acc[3][j] = fmaf(av.w, bb[j], acc[3][j]);
                }
            }
        }
    }
    // epilogue: +bias, store float4 along w
    #pragma unroll
    for (int j = 0; j < 8; ++j) {
        int oc = ocg * 8 + j;
        float bs = bias[oc];
        float4 v;
        v.x = acc[0][j] + bs;
        v.y = acc[1][j] + bs;
        v.z = acc[2][j] + bs;
        v.w = acc[3][j] + bs;
        *(float4*)&out[(size_t)(b * C2 + oc) * HWn + hw0 + pixg * 4] = v;
    }
}

// ---------------- kernel 3: BN stats (per-channel mean, invstd) ----------------
__global__ __launch_bounds__(256) void k_bnstats(const float* __restrict__ out,
                                                 float* __restrict__ stats)
{
    int oc = blockIdx.x;
    double s = 0.0, ss = 0.0;
    for (int i = threadIdx.x; i < NPIX; i += 256) {
        int bb = i / HWn;
        int hw = i - bb * HWn;
        float v = out[(size_t)(bb * C2 + oc) * HWn + hw];
        s  += (double)v;
        ss += (double)v * (double)v;
    }
    __shared__ double ls[256], lss[256];
    ls[threadIdx.x] = s; lss[threadIdx.x] = ss;
    __syncthreads();
    for (int st = 128; st > 0; st >>= 1) {
        if (threadIdx.x < st) {
            ls[threadIdx.x]  += ls[threadIdx.x + st];
            lss[threadIdx.x] += lss[threadIdx.x + st];
        }
        __syncthreads();
    }
    if (threadIdx.x == 0) {
        double mean = ls[0] / (double)NPIX;
        double var  = lss[0] / (double)NPIX - mean * mean;
        stats[oc]       = (float)mean;
        stats[256 + oc] = (float)(1.0 / sqrt(var + 1e-5));
    }
}

// ---------------- kernel 4: BN normalize + affine + SiLU (in-place) ----------------
__global__ __launch_bounds__(256) void k_bnsilu(float* __restrict__ out,
                                                const float* __restrict__ stats,
                                                const float* __restrict__ gamma,
                                                const float* __restrict__ beta)
{
    int n4 = (Bn * C2 * HWn) / 4;
    for (int i = blockIdx.x * blockDim.x + threadIdx.x; i < n4;
         i += gridDim.x * blockDim.x) {
        float4 v = ((float4*)out)[i];
        int e  = i * 4;
        int oc = (e / HWn) & 255;
        float mean = stats[oc];
        float gs   = gamma[oc] * stats[256 + oc];
        float bt   = beta[oc];
        float y;
        y = (v.x - mean) * gs + bt; v.x = y / (1.f + expf(-y));
        y = (v.y - mean) * gs + bt; v.y = y / (1.f + expf(-y));
        y = (v.z - mean) * gs + bt; v.z = y / (1.f + expf(-y));
        y = (v.w - mean) * gs + bt; v.w = y / (1.f + expf(-y));
        ((float4*)out)[i] = v;
    }
}

extern "C" void kernel_launch(void* const* d_in, const int* in_sizes, int n_in,
                              void* d_out, int out_size, void* d_ws, size_t ws_size,
                              hipStream_t stream)
{
    const float* x      = (const float*)d_in[0];
    const float* w_off  = (const float*)d_in[1];
    const float* b_off  = (const float*)d_in[2];
    const float* weight = (const float*)d_in[3];
    const float* bias   = (const float*)d_in[4];
    const float* gamma  = (const float*)d_in[5];
    const float* beta   = (const float*)d_in[6];
    float* out = (float*)d_out;

    float* ws    = (float*)d_ws;
    float* off   = ws;                       // 691200 floats
    float* wT    = ws + 691200;              // 589824 floats
    float* stats = ws + 691200 + 589824;     // 512 floats
    // total ws usage: ~5.13 MB

    k_wtrans   <<<2304, 256, 0, stream>>>(weight, wT);
    k_offinit  <<<2700, 256, 0, stream>>>(b_off, off);
    k_offconv2 <<<400, 256, 0, stream>>>(x, w_off, off);
    k_dconv    <<<NPIX / 32, 256, 0, stream>>>(x, off, wT, bias, out);
    k_bnstats  <<<256, 256, 0, stream>>>(out, stats);
    k_bnsilu   <<<2048, 256, 0, stream>>>(out, stats, gamma, beta);
}

// Round 4
// 583.701 us; speedup vs baseline: 2.4876x; 1.8455x over previous
//
#include <hip/hip_runtime.h>
#include <math.h>

constexpr int Hc = 80, Wc = 80, Bn = 4, C1 = 256, C2 = 256;
constexpr int HWn = Hc * Wc;          // 6400
constexpr int NPIX = Bn * HWn;        // 25600
constexpr int OFFC = 27;

typedef short bf16x8 __attribute__((ext_vector_type(8)));
typedef float f32x4  __attribute__((ext_vector_type(4)));

__device__ __forceinline__ unsigned f2bf(float f) {   // RNE to bf16 bits
    unsigned u = __float_as_uint(f);
    return (u + 0x7FFF + ((u >> 16) & 1)) >> 16;
}
__device__ __forceinline__ float bf2f(unsigned b) { return __uint_as_float(b << 16); }

// ---------------- kernel 0: weight prep -> per-step LDS images ----------------
// wB[s][split][oc][40] bf16, s = p*8+cc (72 steps), kc<32 real, kc>=32 pad=0
__global__ __launch_bounds__(256) void k_wprep(const float* __restrict__ weight,
                                               unsigned short* __restrict__ wB)
{
    int e = blockIdx.x * 256 + threadIdx.x;   // 0 .. 1474559
    int kc = e % 40;
    int oc = (e / 40) & 255;
    int sp = (e / 10240) & 1;
    int s  = e / 20480;
    int p  = s >> 3, cc = s & 7;
    float w = 0.f;
    if (kc < 32) w = weight[((size_t)oc * C1 + cc * 32 + kc) * 9 + p];
    unsigned hb = f2bf(w);
    unsigned val = sp ? f2bf(w - bf2f(hb)) : hb;
    wB[e] = (unsigned short)val;
}

// ---------------- kernel 1a: init off buffer with b_off ----------------
__global__ __launch_bounds__(256) void k_offinit(const float* __restrict__ b_off,
                                                 float* __restrict__ off)
{
    int t = blockIdx.x * 256 + threadIdx.x;   // 0 .. 691199
    int ch = (t / HWn) % OFFC;
    off[t] = b_off[ch];
}

// ---------------- kernel 1b: offset conv (LDS-tiled, c-split 8) ----------------
__global__ __launch_bounds__(256) void k_offconv2(const float* __restrict__ x,
                                                  const float* __restrict__ w_off,
                                                  float* __restrict__ off)
{
    __shared__ float xs[8][18][18];

    int tid  = threadIdx.x;
    int bidx = blockIdx.x;                 // 0..799
    int wt = bidx % 5;
    int ht = (bidx / 5) % 5;
    int b  = (bidx / 25) % 4;
    int cg = bidx / 100;                   // 0..7
    int h0 = ht * 16, w0 = wt * 16;
    int c0 = cg * 32;
    int ph = tid >> 4, pw = tid & 15;

    float acc[27];
    #pragma unroll
    for (int ch = 0; ch < 27; ++ch) acc[ch] = 0.f;

    const float* xb = x + (size_t)b * C1 * HWn;

    for (int cc = 0; cc < 4; ++cc) {       // 4 chunks of 8 channels
        __syncthreads();
        for (int idx = tid; idx < 8 * 324; idx += 256) {
            int cl  = idx / 324;
            int rem = idx - cl * 324;
            int r   = rem / 18;
            int col = rem - r * 18;
            int gh = h0 - 1 + r, gw = w0 - 1 + col;
            float v = 0.f;
            if (gh >= 0 && gh < Hc && gw >= 0 && gw < Wc)
                v = xb[(size_t)(c0 + cc * 8 + cl) * HWn + gh * Wc + gw];
            xs[cl][r][col] = v;
        }
        __syncthreads();
        #pragma unroll
        for (int cl = 0; cl < 8; ++cl) {
            float xr[9];
            #pragma unroll
            for (int kh = 0; kh < 3; ++kh)
                #pragma unroll
                for (int kw = 0; kw < 3; ++kw)
                    xr[kh * 3 + kw] = xs[cl][ph + kh][pw + kw];
            int c = c0 + cc * 8 + cl;
            const float* wp = w_off + (size_t)c * 9;
            #pragma unroll
            for (int ch = 0; ch < 27; ++ch) {
                const float* wc = wp + (size_t)ch * C1 * 9;  // uniform -> s_load
                #pragma unroll
                for (int p = 0; p < 9; ++p)
                    acc[ch] = fmaf(xr[p], wc[p], acc[ch]);
            }
        }
    }

    int hw = (h0 + ph) * Wc + (w0 + pw);
    float* ob = off + (size_t)b * OFFC * HWn + hw;
    #pragma unroll
    for (int ch = 0; ch < 27; ++ch)
        atomicAdd(ob + (size_t)ch * HWn, acc[ch]);
}

// ------------- kernel 2: deformable gather + split-bf16 MFMA GEMM -------------
// M=25600 pixels, N=256 oc, K=2304 (p-major). BM=64, BN=256, BK=32.
// 256 threads = 4 waves; wave = 32pix x 128oc (2 m-tiles x 8 n-tiles of 16x16).
// A split hi/lo bf16; 3 MFMA per tile (AhBh + AhBl + AlBh) ~ fp32 accuracy.
__global__ __launch_bounds__(256) void k_dmfma(const float* __restrict__ x,
                                               const float* __restrict__ off,
                                               const unsigned short* __restrict__ wB,
                                               const float* __restrict__ bias,
                                               float* __restrict__ out)
{
    // LDS map (bytes):
    //   0     Ahi [64][40] u16   (5120)
    //   5120  Alo [64][40] u16   (5120)
    //   10240 crd [576] int      (2304)
    //   12544 w4  [576] float4   (9216)
    //   21760 B   [2][256][40] u16 (40960)   total 62720
    //   epilogue: Tb [64][66] f32 (16896) aliases 0..16896
    __shared__ __align__(16) char smem[62720];
    unsigned short* Ahi = (unsigned short*)(smem);
    unsigned short* Alo = (unsigned short*)(smem + 5120);
    int*    crd = (int*)(smem + 10240);
    float4* w4  = (float4*)(smem + 12544);
    unsigned short* Bhi = (unsigned short*)(smem + 21760);
    unsigned short* Blo = Bhi + 10240;
    float*  Tb  = (float*)(smem);

    int t  = threadIdx.x;
    int m0 = blockIdx.x * 64;
    int b  = m0 / HWn;                 // uniform (6400 % 64 == 0)
    int hw0 = m0 - b * HWn;
    const float* xb = x + (size_t)b * C1 * HWn;

    // ---- per-(pixel, p) bilinear metadata ----
    for (int idx = t; idx < 576; idx += 256) {
        int pix = idx / 9;
        int p   = idx - pix * 9;
        int hw  = hw0 + pix;
        int h = hw / Wc, w = hw - h * Wc;
        int ii = p / 3, jj = p - ii * 3;
        const float* ob = off + (size_t)b * OFFC * HWn + hw;
        float dy = ob[(2 * p) * HWn];
        float dx = ob[(2 * p + 1) * HWn];
        float mv = ob[(18 + p) * HWn];
        float mask = 1.0f / (1.0f + expf(-mv));
        float ys = dy + (float)(h - 1 + ii);
        float xs = dx + (float)(w - 1 + jj);
        float y0f = floorf(ys), x0f = floorf(xs);
        float wy = ys - y0f, wx = xs - x0f;
        int y0 = (int)y0f, x0 = (int)x0f;
        int y1 = y0 + 1, x1 = x0 + 1;
        float vy0 = (y0 >= 0 && y0 < Hc) ? 1.f : 0.f;
        float vy1 = (y1 >= 0 && y1 < Hc) ? 1.f : 0.f;
        float vx0 = (x0 >= 0 && x0 < Wc) ? 1.f : 0.f;
        float vx1 = (x1 >= 0 && x1 < Wc) ? 1.f : 0.f;
        float4 wv;
        wv.x = mask * (1.f - wy) * (1.f - wx) * vy0 * vx0;
        wv.y = mask * (1.f - wy) * wx         * vy0 * vx1;
        wv.z = mask * wy         * (1.f - wx) * vy1 * vx0;
        wv.w = mask * wy         * wx         * vy1 * vx1;
        int cy0 = min(max(y0, 0), Hc - 1), cy1 = min(max(y1, 0), Hc - 1);
        int cx0 = min(max(x0, 0), Wc - 1), cx1 = min(max(x1, 0), Wc - 1);
        crd[idx] = cy0 | (cy1 << 8) | (cx0 << 16) | (cx1 << 24);
        w4[idx]  = wv;
    }
    __syncthreads();

    f32x4 acc[2][8];
    #pragma unroll
    for (int m = 0; m < 2; ++m)
        #pragma unroll
        for (int n = 0; n < 8; ++n)
            acc[m][n] = (f32x4){0.f, 0.f, 0.f, 0.f};

    int wave = t >> 6, lane = t & 63;
    int mhalf = wave & 1, nhalf = wave >> 1;
    int kg = lane >> 4, li = lane & 15;
    int pix_s = t & 63, cgrp = t >> 6;

    for (int s = 0; s < 72; ++s) {
        int p  = s >> 3;
        int c0 = (s & 7) << 5;
        __syncthreads();                       // prev step's MFMA reads done
        // ---- stage B: linear copy of pre-built LDS image (40960 B) ----
        const float4* bsrc = (const float4*)(wB + (size_t)s * 20480);
        float4* bdst = (float4*)(smem + 21760);
        #pragma unroll
        for (int i = 0; i < 10; ++i)
            bdst[t + 256 * i] = bsrc[t + 256 * i];
        // ---- stage A: bilinear gather -> hi/lo bf16 ----
        {
            int cr = crd[pix_s * 9 + p];
            float4 wv = w4[pix_s * 9 + p];
            int cy0 = cr & 255, cy1 = (cr >> 8) & 255;
            int cx0 = (cr >> 16) & 255, cx1 = (cr >> 24) & 255;
            int o00 = cy0 * Wc + cx0, o01 = cy0 * Wc + cx1;
            int o10 = cy1 * Wc + cx0, o11 = cy1 * Wc + cx1;
            unsigned hu[4], lu[4];
            const float* xp = xb + (size_t)(c0 + cgrp * 8) * HWn;
            #pragma unroll
            for (int i = 0; i < 8; ++i) {
                float v = wv.x * xp[o00] + wv.y * xp[o01]
                        + wv.z * xp[o10] + wv.w * xp[o11];
                unsigned hb = f2bf(v);
                unsigned lb = f2bf(v - bf2f(hb));
                if (i & 1) { hu[i >> 1] |= hb << 16; lu[i >> 1] |= lb << 16; }
                else       { hu[i >> 1] = hb;        lu[i >> 1] = lb; }
                xp += HWn;
            }
            *(uint4*)&Ahi[pix_s * 40 + cgrp * 8] = make_uint4(hu[0], hu[1], hu[2], hu[3]);
            *(uint4*)&Alo[pix_s * 40 + cgrp * 8] = make_uint4(lu[0], lu[1], lu[2], lu[3]);
        }
        __syncthreads();
        // ---- MFMA phase ----
        bf16x8 ah0 = *(const bf16x8*)&Ahi[(mhalf * 32 + li) * 40 + kg * 8];
        bf16x8 ah1 = *(const bf16x8*)&Ahi[(mhalf * 32 + 16 + li) * 40 + kg * 8];
        bf16x8 al0 = *(const bf16x8*)&Alo[(mhalf * 32 + li) * 40 + kg * 8];
        bf16x8 al1 = *(const bf16x8*)&Alo[(mhalf * 32 + 16 + li) * 40 + kg * 8];
        #pragma unroll
        for (int nt = 0; nt < 8; ++nt) {
            int oc = nhalf * 128 + nt * 16 + li;
            bf16x8 bh = *(const bf16x8*)&Bhi[oc * 40 + kg * 8];
            bf16x8 bl = *(const bf16x8*)&Blo[oc * 40 + kg * 8];
            acc[0][nt] = __builtin_amdgcn_mfma_f32_16x16x32_bf16(ah0, bh, acc[0][nt], 0, 0, 0);
            acc[0][nt] = __builtin_amdgcn_mfma_f32_16x16x32_bf16(ah0, bl, acc[0][nt], 0, 0, 0);
            acc[0][nt] = __builtin_amdgcn_mfma_f32_16x16x32_bf16(al0, bh, acc[0][nt], 0, 0, 0);
            acc[1][nt] = __builtin_amdgcn_mfma_f32_16x16x32_bf16(ah1, bh, acc[1][nt], 0, 0, 0);
            acc[1][nt] = __builtin_amdgcn_mfma_f32_16x16x32_bf16(ah1, bl, acc[1][nt], 0, 0, 0);
            acc[1][nt] = __builtin_amdgcn_mfma_f32_16x16x32_bf16(al1, bh, acc[1][nt], 0, 0, 0);
        }
    }

    // ---- epilogue: 4-phase LDS transpose -> coalesced stores ----
    for (int q = 0; q < 4; ++q) {
        __syncthreads();
        #pragma unroll
        for (int mt = 0; mt < 2; ++mt)
            #pragma unroll
            for (int j = 0; j < 2; ++j) {
                f32x4 a = acc[mt][2 * q + j];
                int ocl = nhalf * 32 + j * 16 + li;          // 0..63
                int pxl = mhalf * 32 + mt * 16 + kg * 4;
                #pragma unroll
                for (int r = 0; r < 4; ++r)
                    Tb[ocl * 66 + pxl + r] = a[r];
            }
        __syncthreads();
        for (int rr = t >> 6; rr < 64; rr += 4) {
            int oc = (rr >> 5) * 128 + q * 32 + (rr & 31);
            float v = Tb[rr * 66 + (t & 63)] + bias[oc];
            out[(size_t)(b * C2 + oc) * HWn + hw0 + (t & 63)] = v;
        }
    }
}

// ---------------- kernel 3: BN stats (per-channel mean, invstd) ----------------
__global__ __launch_bounds__(256) void k_bnstats(const float* __restrict__ out,
                                                 float* __restrict__ stats)
{
    int oc = blockIdx.x;
    double s = 0.0, ss = 0.0;
    for (int i = threadIdx.x; i < NPIX; i += 256) {
        int bb = i / HWn;
        int hw = i - bb * HWn;
        float v = out[(size_t)(bb * C2 + oc) * HWn + hw];
        s  += (double)v;
        ss += (double)v * (double)v;
    }
    __shared__ double ls[256], lss[256];
    ls[threadIdx.x] = s; lss[threadIdx.x] = ss;
    __syncthreads();
    for (int st = 128; st > 0; st >>= 1) {
        if (threadIdx.x < st) {
            ls[threadIdx.x]  += ls[threadIdx.x + st];
            lss[threadIdx.x] += lss[threadIdx.x + st];
        }
        __syncthreads();
    }
    if (threadIdx.x == 0) {
        double mean = ls[0] / (double)NPIX;
        double var  = lss[0] / (double)NPIX - mean * mean;
        stats[oc]       = (float)mean;
        stats[256 + oc] = (float)(1.0 / sqrt(var + 1e-5));
    }
}

// ---------------- kernel 4: BN normalize + affine + SiLU (in-place) ----------------
__global__ __launch_bounds__(256) void k_bnsilu(float* __restrict__ out,
                                                const float* __restrict__ stats,
                                                const float* __restrict__ gamma,
                                                const float* __restrict__ beta)
{
    int n4 = (Bn * C2 * HWn) / 4;
    for (int i = blockIdx.x * blockDim.x + threadIdx.x; i < n4;
         i += gridDim.x * blockDim.x) {
        float4 v = ((float4*)out)[i];
        int e  = i * 4;
        int oc = (e / HWn) & 255;
        float mean = stats[oc];
        float gs   = gamma[oc] * stats[256 + oc];
        float bt   = beta[oc];
        float y;
        y = (v.x - mean) * gs + bt; v.x = y / (1.f + expf(-y));
        y = (v.y - mean) * gs + bt; v.y = y / (1.f + expf(-y));
        y = (v.z - mean) * gs + bt; v.z = y / (1.f + expf(-y));
        y = (v.w - mean) * gs + bt; v.w = y / (1.f + expf(-y));
        ((float4*)out)[i] = v;
    }
}

extern "C" void kernel_launch(void* const* d_in, const int* in_sizes, int n_in,
                              void* d_out, int out_size, void* d_ws, size_t ws_size,
                              hipStream_t stream)
{
    const float* x      = (const float*)d_in[0];
    const float* w_off  = (const float*)d_in[1];
    const float* b_off  = (const float*)d_in[2];
    const float* weight = (const float*)d_in[3];
    const float* bias   = (const float*)d_in[4];
    const float* gamma  = (const float*)d_in[5];
    const float* beta   = (const float*)d_in[6];
    float* out = (float*)d_out;

    float* ws    = (float*)d_ws;
    float* off   = ws;                                       // 691200 f
    unsigned short* wB = (unsigned short*)(ws + 691200);     // 1474560 u16
    float* stats = (float*)((char*)d_ws + 5713920);          // 512 f
    // total ws usage: ~5.7 MB

    k_wprep    <<<5760, 256, 0, stream>>>(weight, wB);
    k_offinit  <<<2700, 256, 0, stream>>>(b_off, off);
    k_offconv2 <<<800, 256, 0, stream>>>(x, w_off, off);
    k_dmfma    <<<NPIX / 64, 256, 0, stream>>>(x, off, wB, bias, out);
    k_bnstats  <<<256, 256, 0, stream>>>(out, stats);
    k_bnsilu   <<<2048, 256, 0, stream>>>(out, stats, gamma, beta);
}

// Round 5
// 569.188 us; speedup vs baseline: 2.5510x; 1.0255x over previous
//
#include <hip/hip_runtime.h>
#include <math.h>

constexpr int Hc = 80, Wc = 80, Bn = 4, C1 = 256, C2 = 256;
constexpr int HWn = Hc * Wc;          // 6400
constexpr int NPIX = Bn * HWn;        // 25600
constexpr int OFFC = 27;

typedef short bf16x8 __attribute__((ext_vector_type(8)));
typedef float f32x4  __attribute__((ext_vector_type(4)));

__device__ __forceinline__ unsigned f2bf(float f) {   // RNE to bf16 bits
    unsigned u = __float_as_uint(f);
    return (u + 0x7FFF + ((u >> 16) & 1)) >> 16;
}
__device__ __forceinline__ float bf2f(unsigned b) { return __uint_as_float(b << 16); }

// ---------------- kernel 0: weight prep -> per-step LDS images ----------------
// wB[s][split][oc][40] bf16, s = p*8+cc (72 steps), kc<32 real, kc>=32 pad=0
__global__ __launch_bounds__(256) void k_wprep(const float* __restrict__ weight,
                                               unsigned short* __restrict__ wB)
{
    int e = blockIdx.x * 256 + threadIdx.x;   // 0 .. 1474559
    int kc = e % 40;
    int oc = (e / 40) & 255;
    int sp = (e / 10240) & 1;
    int s  = e / 20480;
    int p  = s >> 3, cc = s & 7;
    float w = 0.f;
    if (kc < 32) w = weight[((size_t)oc * C1 + cc * 32 + kc) * 9 + p];
    unsigned hb = f2bf(w);
    unsigned val = sp ? f2bf(w - bf2f(hb)) : hb;
    wB[e] = (unsigned short)val;
}

// ---------------- kernel 1a: init off buffer with b_off ----------------
__global__ __launch_bounds__(256) void k_offinit(const float* __restrict__ b_off,
                                                 float* __restrict__ off)
{
    int t = blockIdx.x * 256 + threadIdx.x;   // 0 .. 691199
    int ch = (t / HWn) % OFFC;
    off[t] = b_off[ch];
}

// ---------------- kernel 1b: offset conv (LDS-tiled, c-split 8) ----------------
__global__ __launch_bounds__(256) void k_offconv2(const float* __restrict__ x,
                                                  const float* __restrict__ w_off,
                                                  float* __restrict__ off)
{
    __shared__ float xs[8][18][18];

    int tid  = threadIdx.x;
    int bidx = blockIdx.x;                 // 0..799
    int wt = bidx % 5;
    int ht = (bidx / 5) % 5;
    int b  = (bidx / 25) % 4;
    int cg = bidx / 100;                   // 0..7
    int h0 = ht * 16, w0 = wt * 16;
    int c0 = cg * 32;
    int ph = tid >> 4, pw = tid & 15;

    float acc[27];
    #pragma unroll
    for (int ch = 0; ch < 27; ++ch) acc[ch] = 0.f;

    const float* xb = x + (size_t)b * C1 * HWn;

    for (int cc = 0; cc < 4; ++cc) {       // 4 chunks of 8 channels
        __syncthreads();
        for (int idx = tid; idx < 8 * 324; idx += 256) {
            int cl  = idx / 324;
            int rem = idx - cl * 324;
            int r   = rem / 18;
            int col = rem - r * 18;
            int gh = h0 - 1 + r, gw = w0 - 1 + col;
            float v = 0.f;
            if (gh >= 0 && gh < Hc && gw >= 0 && gw < Wc)
                v = xb[(size_t)(c0 + cc * 8 + cl) * HWn + gh * Wc + gw];
            xs[cl][r][col] = v;
        }
        __syncthreads();
        #pragma unroll
        for (int cl = 0; cl < 8; ++cl) {
            float xr[9];
            #pragma unroll
            for (int kh = 0; kh < 3; ++kh)
                #pragma unroll
                for (int kw = 0; kw < 3; ++kw)
                    xr[kh * 3 + kw] = xs[cl][ph + kh][pw + kw];
            int c = c0 + cc * 8 + cl;
            const float* wp = w_off + (size_t)c * 9;
            #pragma unroll
            for (int ch = 0; ch < 27; ++ch) {
                const float* wc = wp + (size_t)ch * C1 * 9;  // uniform -> s_load
                #pragma unroll
                for (int p = 0; p < 9; ++p)
                    acc[ch] = fmaf(xr[p], wc[p], acc[ch]);
            }
        }
    }

    int hw = (h0 + ph) * Wc + (w0 + pw);
    float* ob = off + (size_t)b * OFFC * HWn + hw;
    #pragma unroll
    for (int ch = 0; ch < 27; ++ch)
        atomicAdd(ob + (size_t)ch * HWn, acc[ch]);
}

// ------------- kernel 2: deformable gather + split-bf16 MFMA GEMM -------------
// M=25600 pixels, N=256 oc, K=2304 (p-major). BM=64, BN=256, BK=32.
// 256 threads = 4 waves; wave = 32pix x 128oc (2 m-tiles x 8 n-tiles of 16x16).
// A split hi/lo bf16; 3 MFMA per tile (AhBh + AhBl + AlBh) ~ fp32 accuracy.
// XCD-chunked swizzle: each XCD owns 50 contiguous M-tiles -> wB + x slice
// stay resident in its private 4MB L2 (round-4 counters: 567MB HBM refetch).
__global__ __launch_bounds__(256) void k_dmfma(const float* __restrict__ x,
                                               const float* __restrict__ off,
                                               const unsigned short* __restrict__ wB,
                                               const float* __restrict__ bias,
                                               float* __restrict__ out)
{
    // LDS map (bytes):
    //   0     Ahi [64][40] u16   (5120)
    //   5120  Alo [64][40] u16   (5120)
    //   10240 crd [576] int      (2304)
    //   12544 w4  [576] float4   (9216)
    //   21760 B   [2][256][40] u16 (40960)   total 62720
    //   epilogue: Tb [64][66] f32 (16896) aliases 0..16896
    __shared__ __align__(16) char smem[62720];
    unsigned short* Ahi = (unsigned short*)(smem);
    unsigned short* Alo = (unsigned short*)(smem + 5120);
    int*    crd = (int*)(smem + 10240);
    float4* w4  = (float4*)(smem + 12544);
    unsigned short* Bhi = (unsigned short*)(smem + 21760);
    unsigned short* Blo = Bhi + 10240;
    float*  Tb  = (float*)(smem);

    int t  = threadIdx.x;
    // XCD-chunked swizzle: blockIdx -> XCD is round-robin (%8); give XCD k
    // the contiguous M-tile range [k*50, (k+1)*50).  400 = 8 * 50 exactly.
    int mtile = ((blockIdx.x & 7) * 50) + (blockIdx.x >> 3);
    int m0 = mtile * 64;
    int b  = m0 / HWn;                 // uniform (6400 % 64 == 0)
    int hw0 = m0 - b * HWn;
    const float* xb = x + (size_t)b * C1 * HWn;

    // ---- per-(pixel, p) bilinear metadata ----
    for (int idx = t; idx < 576; idx += 256) {
        int pix = idx / 9;
        int p   = idx - pix * 9;
        int hw  = hw0 + pix;
        int h = hw / Wc, w = hw - h * Wc;
        int ii = p / 3, jj = p - ii * 3;
        const float* ob = off + (size_t)b * OFFC * HWn + hw;
        float dy = ob[(2 * p) * HWn];
        float dx = ob[(2 * p + 1) * HWn];
        float mv = ob[(18 + p) * HWn];
        float mask = 1.0f / (1.0f + expf(-mv));
        float ys = dy + (float)(h - 1 + ii);
        float xs = dx + (float)(w - 1 + jj);
        float y0f = floorf(ys), x0f = floorf(xs);
        float wy = ys - y0f, wx = xs - x0f;
        int y0 = (int)y0f, x0 = (int)x0f;
        int y1 = y0 + 1, x1 = x0 + 1;
        float vy0 = (y0 >= 0 && y0 < Hc) ? 1.f : 0.f;
        float vy1 = (y1 >= 0 && y1 < Hc) ? 1.f : 0.f;
        float vx0 = (x0 >= 0 && x0 < Wc) ? 1.f : 0.f;
        float vx1 = (x1 >= 0 && x1 < Wc) ? 1.f : 0.f;
        float4 wv;
        wv.x = mask * (1.f - wy) * (1.f - wx) * vy0 * vx0;
        wv.y = mask * (1.f - wy) * wx         * vy0 * vx1;
        wv.z = mask * wy         * (1.f - wx) * vy1 * vx0;
        wv.w = mask * wy         * wx         * vy1 * vx1;
        int cy0 = min(max(y0, 0), Hc - 1), cy1 = min(max(y1, 0), Hc - 1);
        int cx0 = min(max(x0, 0), Wc - 1), cx1 = min(max(x1, 0), Wc - 1);
        crd[idx] = cy0 | (cy1 << 8) | (cx0 << 16) | (cx1 << 24);
        w4[idx]  = wv;
    }
    __syncthreads();

    f32x4 acc[2][8];
    #pragma unroll
    for (int m = 0; m < 2; ++m)
        #pragma unroll
        for (int n = 0; n < 8; ++n)
            acc[m][n] = (f32x4){0.f, 0.f, 0.f, 0.f};

    int wave = t >> 6, lane = t & 63;
    int mhalf = wave & 1, nhalf = wave >> 1;
    int kg = lane >> 4, li = lane & 15;
    int pix_s = t & 63, cgrp = t >> 6;

    for (int s = 0; s < 72; ++s) {
        int p  = s >> 3;
        int c0 = (s & 7) << 5;
        __syncthreads();                       // prev step's MFMA reads done
        // ---- stage B: linear copy of pre-built LDS image (40960 B) ----
        const float4* bsrc = (const float4*)(wB + (size_t)s * 20480);
        float4* bdst = (float4*)(smem + 21760);
        #pragma unroll
        for (int i = 0; i < 10; ++i)
            bdst[t + 256 * i] = bsrc[t + 256 * i];
        // ---- stage A: bilinear gather -> hi/lo bf16 ----
        {
            int cr = crd[pix_s * 9 + p];
            float4 wv = w4[pix_s * 9 + p];
            int cy0 = cr & 255, cy1 = (cr >> 8) & 255;
            int cx0 = (cr >> 16) & 255, cx1 = (cr >> 24) & 255;
            int o00 = cy0 * Wc + cx0, o01 = cy0 * Wc + cx1;
            int o10 = cy1 * Wc + cx0, o11 = cy1 * Wc + cx1;
            unsigned hu[4], lu[4];
            const float* xp = xb + (size_t)(c0 + cgrp * 8) * HWn;
            #pragma unroll
            for (int i = 0; i < 8; ++i) {
                float v = wv.x * xp[o00] + wv.y * xp[o01]
                        + wv.z * xp[o10] + wv.w * xp[o11];
                unsigned hb = f2bf(v);
                unsigned lb = f2bf(v - bf2f(hb));
                if (i & 1) { hu[i >> 1] |= hb << 16; lu[i >> 1] |= lb << 16; }
                else       { hu[i >> 1] = hb;        lu[i >> 1] = lb; }
                xp += HWn;
            }
            *(uint4*)&Ahi[pix_s * 40 + cgrp * 8] = make_uint4(hu[0], hu[1], hu[2], hu[3]);
            *(uint4*)&Alo[pix_s * 40 + cgrp * 8] = make_uint4(lu[0], lu[1], lu[2], lu[3]);
        }
        __syncthreads();
        // ---- MFMA phase ----
        bf16x8 ah0 = *(const bf16x8*)&Ahi[(mhalf * 32 + li) * 40 + kg * 8];
        bf16x8 ah1 = *(const bf16x8*)&Ahi[(mhalf * 32 + 16 + li) * 40 + kg * 8];
        bf16x8 al0 = *(const bf16x8*)&Alo[(mhalf * 32 + li) * 40 + kg * 8];
        bf16x8 al1 = *(const bf16x8*)&Alo[(mhalf * 32 + 16 + li) * 40 + kg * 8];
        #pragma unroll
        for (int nt = 0; nt < 8; ++nt) {
            int oc = nhalf * 128 + nt * 16 + li;
            bf16x8 bh = *(const bf16x8*)&Bhi[oc * 40 + kg * 8];
            bf16x8 bl = *(const bf16x8*)&Blo[oc * 40 + kg * 8];
            acc[0][nt] = __builtin_amdgcn_mfma_f32_16x16x32_bf16(ah0, bh, acc[0][nt], 0, 0, 0);
            acc[0][nt] = __builtin_amdgcn_mfma_f32_16x16x32_bf16(ah0, bl, acc[0][nt], 0, 0, 0);
            acc[0][nt] = __builtin_amdgcn_mfma_f32_16x16x32_bf16(al0, bh, acc[0][nt], 0, 0, 0);
            acc[1][nt] = __builtin_amdgcn_mfma_f32_16x16x32_bf16(ah1, bh, acc[1][nt], 0, 0, 0);
            acc[1][nt] = __builtin_amdgcn_mfma_f32_16x16x32_bf16(ah1, bl, acc[1][nt], 0, 0, 0);
            acc[1][nt] = __builtin_amdgcn_mfma_f32_16x16x32_bf16(al1, bh, acc[1][nt], 0, 0, 0);
        }
    }

    // ---- epilogue: 4-phase LDS transpose -> coalesced stores ----
    for (int q = 0; q < 4; ++q) {
        __syncthreads();
        #pragma unroll
        for (int mt = 0; mt < 2; ++mt)
            #pragma unroll
            for (int j = 0; j < 2; ++j) {
                f32x4 a = acc[mt][2 * q + j];
                int ocl = nhalf * 32 + j * 16 + li;          // 0..63
                int pxl = mhalf * 32 + mt * 16 + kg * 4;
                #pragma unroll
                for (int r = 0; r < 4; ++r)
                    Tb[ocl * 66 + pxl + r] = a[r];
            }
        __syncthreads();
        for (int rr = t >> 6; rr < 64; rr += 4) {
            int oc = (rr >> 5) * 128 + q * 32 + (rr & 31);
            float v = Tb[rr * 66 + (t & 63)] + bias[oc];
            out[(size_t)(b * C2 + oc) * HWn + hw0 + (t & 63)] = v;
        }
    }
}

// ---------------- kernel 3: BN stats (per-channel mean, invstd) ----------------
__global__ __launch_bounds__(256) void k_bnstats(const float* __restrict__ out,
                                                 float* __restrict__ stats)
{
    int oc = blockIdx.x;
    double s = 0.0, ss = 0.0;
    for (int i = threadIdx.x; i < NPIX; i += 256) {
        int bb = i / HWn;
        int hw = i - bb * HWn;
        float v = out[(size_t)(bb * C2 + oc) * HWn + hw];
        s  += (double)v;
        ss += (double)v * (double)v;
    }
    __shared__ double ls[256], lss[256];
    ls[threadIdx.x] = s; lss[threadIdx.x] = ss;
    __syncthreads();
    for (int st = 128; st > 0; st >>= 1) {
        if (threadIdx.x < st) {
            ls[threadIdx.x]  += ls[threadIdx.x + st];
            lss[threadIdx.x] += lss[threadIdx.x + st];
        }
        __syncthreads();
    }
    if (threadIdx.x == 0) {
        double mean = ls[0] / (double)NPIX;
        double var  = lss[0] / (double)NPIX - mean * mean;
        stats[oc]       = (float)mean;
        stats[256 + oc] = (float)(1.0 / sqrt(var + 1e-5));
    }
}

// ---------------- kernel 4: BN normalize + affine + SiLU (in-place) ----------------
__global__ __launch_bounds__(256) void k_bnsilu(float* __restrict__ out,
                                                const float* __restrict__ stats,
                                                const float* __restrict__ gamma,
                                                const float* __restrict__ beta)
{
    int n4 = (Bn * C2 * HWn) / 4;
    for (int i = blockIdx.x * blockDim.x + threadIdx.x; i < n4;
         i += gridDim.x * blockDim.x) {
        float4 v = ((float4*)out)[i];
        int e  = i * 4;
        int oc = (e / HWn) & 255;
        float mean = stats[oc];
        float gs   = gamma[oc] * stats[256 + oc];
        float bt   = beta[oc];
        float y;
        y = (v.x - mean) * gs + bt; v.x = y / (1.f + expf(-y));
        y = (v.y - mean) * gs + bt; v.y = y / (1.f + expf(-y));
        y = (v.z - mean) * gs + bt; v.z = y / (1.f + expf(-y));
        y = (v.w - mean) * gs + bt; v.w = y / (1.f + expf(-y));
        ((float4*)out)[i] = v;
    }
}

extern "C" void kernel_launch(void* const* d_in, const int* in_sizes, int n_in,
                              void* d_out, int out_size, void* d_ws, size_t ws_size,
                              hipStream_t stream)
{
    const float* x      = (const float*)d_in[0];
    const float* w_off  = (const float*)d_in[1];
    const float* b_off  = (const float*)d_in[2];
    const float* weight = (const float*)d_in[3];
    const float* bias   = (const float*)d_in[4];
    const float* gamma  = (const float*)d_in[5];
    const float* beta   = (const float*)d_in[6];
    float* out = (float*)d_out;

    float* ws    = (float*)d_ws;
    float* off   = ws;                                       // 691200 f
    unsigned short* wB = (unsigned short*)(ws + 691200);     // 1474560 u16
    float* stats = (float*)((char*)d_ws + 5713920);          // 512 f
    // total ws usage: ~5.7 MB

    k_wprep    <<<5760, 256, 0, stream>>>(weight, wB);
    k_offinit  <<<2700, 256, 0, stream>>>(b_off, off);
    k_offconv2 <<<800, 256, 0, stream>>>(x, w_off, off);
    k_dmfma    <<<NPIX / 64, 256, 0, stream>>>(x, off, wB, bias, out);
    k_bnstats  <<<256, 256, 0, stream>>>(out, stats);
    k_bnsilu   <<<2048, 256, 0, stream>>>(out, stats, gamma, beta);
}